// Round 5
// baseline (621.921 us; speedup 1.0000x reference)
//
#include <hip/hip_runtime.h>

// ConvSTFT as GEMM: C[b][c][f] = sum_k x_pad[b][f*100+k] * W[c][k]
// B=32, T=480000, WIN=400, HOP=100, C_OUT=514, PAD=300, NF=4803.
//
// R7 == R6 with compile fix (__builtin_nontemporal_store needs a clang
// ext_vector pointer, not HIP float4*).
//   SINGLE FUSED PERSISTENT KERNEL (no workspace, no cvt kernels).
//   grid=256 (1 block/CU), 512 threads (8 waves, 32x32 wave tile).
//   Tiles nt-major: the 54 KB w-tile is converted fp32->bf16 into LDS once
//   per block (<=2x at an nt boundary). x staged fp32->bf16 in-register:
//   float4 loads for seg t+1 issued BEFORE compute of tile t (T14 split),
//   convert + ds_write after compute, one barrier per tile.
//   LDS = 54,272 + 2*26,624 = 107,520 B. Nontemporal epilogue stores.

#define T_LEN   480000
#define NF      4803
#define C_OUT   514
#define HOP     100
#define WIN     400
#define BM      128
#define BN      64
#define WSTR    424                 // padded K stride (53x16B)
#define MT_CNT  38
#define NT_CNT  9
#define NTILES  (NT_CNT * MT_CNT * 32)   // 10,944
#define TPNT    (MT_CNT * 32)            // 1,216 tiles per nt
#define XSEG    13312               // bf16 elems per x buffer (need 13,116)
#define NCHUNK  3280                // ushort4 chunks staged (13,120 elems)
#define XLOC    7                   // per-thread chunks: 512*7 = 3584 >= 3280

typedef __attribute__((ext_vector_type(8))) short short8;
typedef __attribute__((ext_vector_type(4))) float f32x4;

__device__ __forceinline__ unsigned short f2bf(float f) {
    unsigned int u = __float_as_uint(f);
    u += 0x7FFFu + ((u >> 16) & 1u);   // RNE
    return (unsigned short)(u >> 16);
}

// tile index t: nt = t/1216 (slowest), b = (t%1216)/38, mt = t%38 (fastest)
__device__ __forceinline__ void decode_tile(int t, int& nt, int& b, int& mt) {
    nt = t / TPNT;
    const int rem = t - nt * TPNT;
    b  = rem / MT_CNT;
    mt = rem - b * MT_CNT;
}

// convert w[nt] block (64 chans x 400 taps) into LDS [64][WSTR], zero-padded
__device__ __forceinline__ void stage_w(const float* __restrict__ w,
                                        unsigned short* __restrict__ w_s,
                                        int nt, int tid) {
    for (int lin = tid; lin < BN * (WSTR / 4); lin += 512) {
        const int r  = lin / (WSTR / 4);
        const int j  = lin - r * (WSTR / 4);
        const int k0 = j * 4;
        const int c  = nt * BN + r;
        ushort4 h = make_ushort4(0, 0, 0, 0);
        if (c < C_OUT && k0 < WIN) {
            const float4 f = *(const float4*)(w + (size_t)c * WIN + k0);
            h.x = f2bf(f.x); h.y = f2bf(f.y); h.z = f2bf(f.z); h.w = f2bf(f.w);
        }
        *(ushort4*)(w_s + r * WSTR + k0) = h;
    }
}

// predicated load of chunk c of the x-seg starting at elem base (rel. to x[b])
__device__ __forceinline__ float4 load_chunk(const float* __restrict__ xb,
                                             int base, int c) {
    const int g = base + c * 4;
    float4 f;
    if (g >= 0 && g <= T_LEN - 4) {
        f = *(const float4*)(xb + g);
    } else {
        f.x = (g + 0 >= 0 && g + 0 < T_LEN) ? xb[g + 0] : 0.f;
        f.y = (g + 1 >= 0 && g + 1 < T_LEN) ? xb[g + 1] : 0.f;
        f.z = (g + 2 >= 0 && g + 2 < T_LEN) ? xb[g + 2] : 0.f;
        f.w = (g + 3 >= 0 && g + 3 < T_LEN) ? xb[g + 3] : 0.f;
    }
    return f;
}

__global__ __launch_bounds__(512, 1)
void stft_fused(const float* __restrict__ x,
                const float* __restrict__ w,
                float* __restrict__ out) {
    __shared__ unsigned short w_s[BN * WSTR];     // 54,272 B
    __shared__ unsigned short x_s[2][XSEG];       // 2 x 26,624 B  (total 107,520 B)

    const int tid  = threadIdx.x;
    const int lane = tid & 63;
    const int wv   = tid >> 6;       // 0..7

    // contiguous chunking: blocks 0..191 take 43 tiles, 192..255 take 42
    const int id  = blockIdx.x;
    const int t0  = (id < 192) ? id * 43 : 192 * 43 + (id - 192) * 42;
    const int nti = (id < 192) ? 43 : 42;

    int nt, b, mt;
    decode_tile(t0, nt, b, mt);

    // ---- prologue: stage w[nt] and x[t0] -> buf0 (synchronous) ----
    stage_w(w, w_s, nt, tid);
    {
        const float* xb = x + (size_t)b * T_LEN;
        const int base = mt * (BM * HOP) - 300;
        #pragma unroll
        for (int j = 0; j < XLOC; ++j) {
            const int c = tid + j * 512;
            if (c < NCHUNK) {
                const float4 f = load_chunk(xb, base, c);
                ushort4 h;
                h.x = f2bf(f.x); h.y = f2bf(f.y); h.z = f2bf(f.z); h.w = f2bf(f.w);
                *(ushort4*)(x_s[0] + c * 4) = h;
            }
        }
    }
    __syncthreads();

    const int q4 = lane >> 4;
    const int lm = lane & 15;
    const int wr = wv & 3;           // M split: 4 waves x 32 frames
    const int wc = wv >> 2;          // N split: 2 waves x 32 chans

    // A: frame m = wr*32 + mi*16 + lm, k = q4*8 + j  -> x_s[frame*100 + k]
    int aoff[2];
    #pragma unroll
    for (int mi = 0; mi < 2; ++mi) aoff[mi] = (wr * 32 + mi * 16 + lm) * HOP + q4 * 8;
    // B: chan n = wc*32 + ni*16 + lm -> w_s[n*WSTR + k]
    int boff[2];
    #pragma unroll
    for (int ni = 0; ni < 2; ++ni) boff[ni] = (wc * 32 + ni * 16 + lm) * WSTR + q4 * 8;

    int cur = 0;
    for (int ti = 0; ti < nti; ++ti) {
        // ---- issue global loads for next x-seg into registers (before compute) ----
        int nnt = nt, nb = 0, nmt = 0;
        const bool have_next = (ti + 1 < nti);
        float4 r0, r1, r2, r3, r4, r5, r6;
        if (have_next) {
            decode_tile(t0 + ti + 1, nnt, nb, nmt);
            const float* xb = x + (size_t)nb * T_LEN;
            const int base = nmt * (BM * HOP) - 300;
            r0 = load_chunk(xb, base, tid + 0 * 512);
            r1 = load_chunk(xb, base, tid + 1 * 512);
            r2 = load_chunk(xb, base, tid + 2 * 512);
            r3 = load_chunk(xb, base, tid + 3 * 512);
            r4 = load_chunk(xb, base, tid + 4 * 512);
            r5 = load_chunk(xb, base, tid + 5 * 512);
            // chunk 6 may exceed NCHUNK; guard (tid + 3072 < 3280 for tid < 208)
            if (tid + 6 * 512 < NCHUNK) {
                r6 = load_chunk(xb, base, tid + 6 * 512);
            } else {
                r6 = (float4){0.f, 0.f, 0.f, 0.f};
            }
        }

        // ---- compute tile (b, mt) from x_s[cur] ----
        const unsigned short* xs = x_s[cur];
        f32x4 acc[2][2];
        #pragma unroll
        for (int mi = 0; mi < 2; ++mi)
            #pragma unroll
            for (int ni = 0; ni < 2; ++ni)
                acc[mi][ni] = (f32x4){0.f, 0.f, 0.f, 0.f};

        #pragma unroll
        for (int kc = 0; kc < 13; ++kc) {
            const int k = kc * 32;
            union { short8 v; unsigned long long u[2]; } au[2];
            #pragma unroll
            for (int mi = 0; mi < 2; ++mi) {
                const unsigned long long* p = (const unsigned long long*)(xs + aoff[mi] + k);
                au[mi].u[0] = p[0]; au[mi].u[1] = p[1];
            }
            #pragma unroll
            for (int ni = 0; ni < 2; ++ni) {
                const short8 bf = *(const short8*)(&w_s[boff[ni] + k]);   // 16B-aligned
                #pragma unroll
                for (int mi = 0; mi < 2; ++mi)
                    acc[mi][ni] = __builtin_amdgcn_mfma_f32_16x16x32_bf16(au[mi].v, bf, acc[mi][ni], 0, 0, 0);
            }
        }

        // ---- convert + write next seg into the other buffer ----
        if (have_next) {
            unsigned short* xd = x_s[cur ^ 1];
            const float4 rr[XLOC] = {r0, r1, r2, r3, r4, r5, r6};
            #pragma unroll
            for (int j = 0; j < XLOC; ++j) {
                const int c = tid + j * 512;
                if (c < NCHUNK) {
                    ushort4 h;
                    h.x = f2bf(rr[j].x); h.y = f2bf(rr[j].y);
                    h.z = f2bf(rr[j].z); h.w = f2bf(rr[j].w);
                    *(ushort4*)(xd + c * 4) = h;
                }
            }
        }

        // ---- epilogue: C/D row = q4*4+reg = frame, col = lm = channel ----
        float* ob = out + (size_t)b * C_OUT * NF;
        const int f_base = mt * BM + wr * 32 + q4 * 4;
        const int c_base = nt * BN + wc * 32 + lm;
        #pragma unroll
        for (int mi = 0; mi < 2; ++mi) {
            const int fg = f_base + mi * 16;
            const bool fok = (fg + 3 < NF);
            #pragma unroll
            for (int ni = 0; ni < 2; ++ni) {
                const int cg = c_base + ni * 16;
                if (cg < C_OUT) {
                    float* op = ob + (size_t)cg * NF + fg;
                    if (fok) {
                        __builtin_nontemporal_store(acc[mi][ni], (f32x4*)op);
                    } else {
                        #pragma unroll
                        for (int rI = 0; rI < 4; ++rI)
                            if (fg + rI < NF) __builtin_nontemporal_store(acc[mi][ni][rI], op + rI);
                    }
                }
            }
        }

        // ---- barrier: makes next x-seg visible; swap buffers ----
        __syncthreads();
        if (have_next && nnt != nt) {
            // <=1 per block (block-uniform condition): restage w
            stage_w(w, w_s, nnt, tid);
            __syncthreads();
        }
        nt = nnt; b = nb; mt = nmt;
        cur ^= 1;
    }
}

extern "C" void kernel_launch(void* const* d_in, const int* in_sizes, int n_in,
                              void* d_out, int out_size, void* d_ws, size_t ws_size,
                              hipStream_t stream) {
    const float* x = (const float*)d_in[0];   // [32, 480000] fp32
    const float* w = (const float*)d_in[1];   // [514, 1, 400] fp32
    float* out = (float*)d_out;               // [32, 514, 4803] fp32
    (void)d_ws; (void)ws_size;                // no workspace needed

    stft_fused<<<dim3(256), 512, 0, stream>>>(x, w, out);
}

// Round 6
// 460.158 us; speedup vs baseline: 1.3515x; 1.3515x over previous
//
#include <hip/hip_runtime.h>
#include <hip/hip_bf16.h>

// ConvSTFT as GEMM: C[b][c][f] = sum_k x_pad[b][f*100+k] * W[c][k]
// B=32, T=480000, WIN=400, HOP=100, C_OUT=514, PAD=300, NF=4803.
//
// R8: 3-kernel pipeline, persistent gemm at 2 blocks/CU.
//   k1: x fp32 -> padded bf16 (d_ws), k2: w fp32 -> bf16 padded rows.
//   k3: grid=512 persistent blocks (2/CU, 16 waves/CU), 512 thr, 32x32 wave
//       tile. nt-major tile order: w-tile staged ~once per block. Single x
//       buffer (LDS 80,896 B -> exactly 2 blocks/CU); per-tile:
//         compute -> barrier -> issue gl_lds x[t+1] (+w') -> plain stores -> barrier
//       Block A's load-drain stall at the 2nd barrier is hidden by block B's
//       compute (R5 at 1 block/CU had no sibling; R7 counters: all pipes idle).
//       PLAIN stores (not nontemporal): R7 showed nt 16B stores bypass L2
//       merging -> 1.9x write amplification + RMW fetch.

#define T_LEN   480000
#define NF      4803
#define C_OUT   514
#define HOP     100
#define WIN     400
#define BM      128
#define BN      64
#define WSTR    424                 // padded K stride (53x16B)
#define XPS     487040              // per-batch padded x length (elems)
#define XP_TOTAL (32 * XPS)         // 15,585,280 elems
#define WP_ROWS 576
#define WP_ELEMS (WP_ROWS * WSTR)   // 244,224
#define WP_BYTE_OFF ((size_t)XP_TOTAL * 2)
#define WS_NEEDED (WP_BYTE_OFF + (size_t)WP_ELEMS * 2)
#define MT_CNT  38
#define NT_CNT  9
#define NTILES  (NT_CNT * MT_CNT * 32)   // 10,944
#define TPNT    (MT_CNT * 32)            // 1,216 tiles per nt
#define XSEG    13312               // bf16 elems in x buffer (need 13,116)
#define NBLK    512                 // 2 blocks/CU

typedef __attribute__((ext_vector_type(8))) short short8;
typedef __attribute__((ext_vector_type(4))) float f32x4;

__device__ __forceinline__ unsigned short f2bf(float f) {
    unsigned int u = __float_as_uint(f);
    u += 0x7FFFu + ((u >> 16) & 1u);   // RNE
    return (unsigned short)(u >> 16);
}

__device__ __forceinline__ void gl_lds16(const unsigned short* g, unsigned short* l) {
    __builtin_amdgcn_global_load_lds(
        (const __attribute__((address_space(1))) unsigned int*)(g),
        (__attribute__((address_space(3))) unsigned int*)(l), 16, 0, 0);
}

// ---------------- k1: x fp32 -> padded bf16 ----------------
__global__ void cvt_x_kernel(const float* __restrict__ x, unsigned short* __restrict__ xp) {
    const int t = blockIdx.x * 256 + threadIdx.x;     // one ushort4 per thread
    const int b  = t / (XPS / 4);
    const int i4 = t - b * (XPS / 4);
    const int i  = i4 * 4;
    const int g  = i - 300;
    ushort4 h;
    if (g >= 0 && g + 3 < T_LEN) {
        const float4 f = *(const float4*)(x + (size_t)b * T_LEN + g);
        h.x = f2bf(f.x); h.y = f2bf(f.y); h.z = f2bf(f.z); h.w = f2bf(f.w);
    } else {
        const float* xb = x + (size_t)b * T_LEN;
        h.x = (g + 0 >= 0 && g + 0 < T_LEN) ? f2bf(xb[g + 0]) : 0;
        h.y = (g + 1 >= 0 && g + 1 < T_LEN) ? f2bf(xb[g + 1]) : 0;
        h.z = (g + 2 >= 0 && g + 2 < T_LEN) ? f2bf(xb[g + 2]) : 0;
        h.w = (g + 3 >= 0 && g + 3 < T_LEN) ? f2bf(xb[g + 3]) : 0;
    }
    *(ushort4*)(xp + (size_t)b * XPS + i) = h;
}

// ---------------- k2: w fp32 -> padded bf16 ----------------
__global__ void cvt_w_kernel(const float* __restrict__ w, unsigned short* __restrict__ wp) {
    const int t = blockIdx.x * 256 + threadIdx.x;     // one elem per thread
    if (t >= WP_ELEMS) return;
    const int c = t / WSTR;
    const int k = t - c * WSTR;
    wp[t] = (c < C_OUT && k < WIN) ? f2bf(w[(size_t)c * WIN + k]) : 0;
}

// ---------------- k3: persistent GEMM, 2 blocks/CU ----------------
// tile index t: nt = t/1216 (slowest), b = (t%1216)/38, mt = t%38 (fastest)
__device__ __forceinline__ void decode_tile(int t, int& nt, int& b, int& mt) {
    nt = t / TPNT;
    const int rem = t - nt * TPNT;
    b  = rem / MT_CNT;
    mt = rem - b * MT_CNT;
}

__global__ __launch_bounds__(512, 4)   // 4 waves/EU = 16 waves/CU = 2 blocks/CU
void stft_gemm(const unsigned short* __restrict__ xp,
               const unsigned short* __restrict__ wp,
               float* __restrict__ out) {
    __shared__ unsigned short w_s[BN * WSTR];     // 54,272 B
    __shared__ unsigned short x_s[XSEG];          // 26,624 B   (total 80,896 B)

    const int tid  = threadIdx.x;
    const int lane = tid & 63;
    const int wv   = tid >> 6;       // 0..7

    // 10,944 tiles over 512 blocks: blocks 0..191 take 22, rest take 21
    const int id  = blockIdx.x;
    const int t0  = id * 21 + ((id < 192) ? id : 192);
    const int nti = 21 + (id < 192 ? 1 : 0);

    int nt, b, mt;
    decode_tile(t0, nt, b, mt);

    // ---- prologue: stage w[nt] and x[t0] ----
    {
        const unsigned short* wg = wp + (size_t)nt * (BN * WSTR);
        #pragma unroll
        for (int c = wv; c < 53; c += 8) {
            const int idx = (c << 6) + lane;
            gl_lds16(wg + idx * 8, w_s + idx * 8);
        }
        const unsigned short* xg = xp + (size_t)b * XPS + mt * (BM * HOP);
        #pragma unroll
        for (int c = wv; c < 26; c += 8) {
            const int idx = (c << 6) + lane;
            gl_lds16(xg + idx * 8, x_s + idx * 8);
        }
    }
    __syncthreads();

    const int q4 = lane >> 4;
    const int lm = lane & 15;
    const int wr = wv & 3;           // M split: 4 waves x 32 frames
    const int wc = wv >> 2;          // N split: 2 waves x 32 chans

    // A: frame m = wr*32 + mi*16 + lm, k = q4*8 + j  -> x_s[frame*100 + k]
    int aoff[2];
    #pragma unroll
    for (int mi = 0; mi < 2; ++mi) aoff[mi] = (wr * 32 + mi * 16 + lm) * HOP + q4 * 8;
    // B: chan n = wc*32 + ni*16 + lm -> w_s[n*WSTR + k]
    int boff[2];
    #pragma unroll
    for (int ni = 0; ni < 2; ++ni) boff[ni] = (wc * 32 + ni * 16 + lm) * WSTR + q4 * 8;

    for (int ti = 0; ti < nti; ++ti) {
        // ---- compute tile (b, mt) from x_s ----
        f32x4 acc[2][2];
        #pragma unroll
        for (int mi = 0; mi < 2; ++mi)
            #pragma unroll
            for (int ni = 0; ni < 2; ++ni)
                acc[mi][ni] = (f32x4){0.f, 0.f, 0.f, 0.f};

        #pragma unroll
        for (int kc = 0; kc < 13; ++kc) {
            const int k = kc * 32;
            union { short8 v; unsigned long long u[2]; } au[2];
            #pragma unroll
            for (int mi = 0; mi < 2; ++mi) {
                const unsigned long long* p = (const unsigned long long*)(x_s + aoff[mi] + k);
                au[mi].u[0] = p[0]; au[mi].u[1] = p[1];
            }
            #pragma unroll
            for (int ni = 0; ni < 2; ++ni) {
                const short8 bf = *(const short8*)(&w_s[boff[ni] + k]);   // 16B-aligned
                #pragma unroll
                for (int mi = 0; mi < 2; ++mi)
                    acc[mi][ni] = __builtin_amdgcn_mfma_f32_16x16x32_bf16(au[mi].v, bf, acc[mi][ni], 0, 0, 0);
            }
        }

        // ---- barrier: all waves done reading x_s (and w_s) ----
        __syncthreads();

        // ---- issue next tile's staging (overwrite is now safe) ----
        int nnt = nt, nb = 0, nmt = 0;
        const bool have_next = (ti + 1 < nti);
        if (have_next) {
            decode_tile(t0 + ti + 1, nnt, nb, nmt);
            const unsigned short* xg = xp + (size_t)nb * XPS + nmt * (BM * HOP);
            #pragma unroll
            for (int c = wv; c < 26; c += 8) {
                const int idx = (c << 6) + lane;
                gl_lds16(xg + idx * 8, x_s + idx * 8);
            }
            if (nnt != nt) {          // <=1 per block, block-uniform
                const unsigned short* wg = wp + (size_t)nnt * (BN * WSTR);
                #pragma unroll
                for (int c = wv; c < 53; c += 8) {
                    const int idx = (c << 6) + lane;
                    gl_lds16(wg + idx * 8, w_s + idx * 8);
                }
            }
        }

        // ---- epilogue: plain stores (L2 merges the 4x16B chunks per line) ----
        // C/D row = q4*4+reg = frame, col = lm = channel
        float* ob = out + (size_t)b * C_OUT * NF;
        const int f_base = mt * BM + wr * 32 + q4 * 4;
        const int c_base = nt * BN + wc * 32 + lm;
        #pragma unroll
        for (int mi = 0; mi < 2; ++mi) {
            const int fg = f_base + mi * 16;
            const bool fok = (fg + 3 < NF);
            #pragma unroll
            for (int ni = 0; ni < 2; ++ni) {
                const int cg = c_base + ni * 16;
                if (cg < C_OUT) {
                    float* op = ob + (size_t)cg * NF + fg;
                    if (fok) {
                        op[0] = acc[mi][ni][0]; op[1] = acc[mi][ni][1];
                        op[2] = acc[mi][ni][2]; op[3] = acc[mi][ni][3];
                    } else {
                        #pragma unroll
                        for (int rI = 0; rI < 4; ++rI)
                            if (fg + rI < NF) op[rI] = acc[mi][ni][rI];
                    }
                }
            }
        }

        // ---- barrier: drains + publishes next tile's x (and w) ----
        __syncthreads();
        nt = nnt; b = nb; mt = nmt;
    }
}

// ---------------- fallback (R1 kernel) if ws too small ----------------
#define SEG 13120
__global__ __launch_bounds__(256, 2)
void conv_stft_fallback(const float* __restrict__ x,
                        const float* __restrict__ w,
                        float* __restrict__ out) {
    __shared__ short x_s[SEG];
    __shared__ short w_s[BN * WSTR];
    const int tid = threadIdx.x;
    const int nt  = blockIdx.x;
    const int mt  = blockIdx.y;
    const int b   = blockIdx.z;
    const int s0 = mt * (BM * HOP) - 300;
    const float* xb = x + (size_t)b * T_LEN;
    for (int v = tid; v < SEG / 4; v += 256) {
        int g = s0 + v * 4;
        float f0, f1, f2, f3;
        if (g >= 0 && g + 3 < T_LEN) {
            const float4 f = *(const float4*)(xb + g);
            f0 = f.x; f1 = f.y; f2 = f.z; f3 = f.w;
        } else {
            f0 = (g + 0 >= 0 && g + 0 < T_LEN) ? xb[g + 0] : 0.f;
            f1 = (g + 1 >= 0 && g + 1 < T_LEN) ? xb[g + 1] : 0.f;
            f2 = (g + 2 >= 0 && g + 2 < T_LEN) ? xb[g + 2] : 0.f;
            f3 = (g + 3 >= 0 && g + 3 < T_LEN) ? xb[g + 3] : 0.f;
        }
        ushort4 h; h.x = f2bf(f0); h.y = f2bf(f1); h.z = f2bf(f2); h.w = f2bf(f3);
        *(ushort4*)(&x_s[v * 4]) = h;
    }
    for (int s = tid; s < BN * 106; s += 256) {
        const int r  = s / 106;
        const int gk = s - r * 106;
        const int c  = nt * BN + r;
        ushort4 h = make_ushort4(0, 0, 0, 0);
        if (gk < 100 && c < C_OUT) {
            const float4 f = *(const float4*)(w + (size_t)c * WIN + gk * 4);
            h.x = f2bf(f.x); h.y = f2bf(f.y); h.z = f2bf(f.z); h.w = f2bf(f.w);
        }
        if (gk * 4 < WSTR) *(ushort4*)(&w_s[r * WSTR + gk * 4]) = h;
    }
    __syncthreads();
    const int lane = tid & 63, wv = tid >> 6, q = lane >> 4, lm = lane & 15;
    f32x4 acc[2][4];
    #pragma unroll
    for (int mi = 0; mi < 2; ++mi)
        #pragma unroll
        for (int ni = 0; ni < 4; ++ni) acc[mi][ni] = (f32x4){0.f,0.f,0.f,0.f};
    const int a0 = (wv * 32 + lm) * HOP + q * 8;
    const int a1 = a0 + 16 * HOP;
    int boff[4];
    #pragma unroll
    for (int ni = 0; ni < 4; ++ni) boff[ni] = (ni * 16 + lm) * WSTR + q * 8;
    #pragma unroll
    for (int kc = 0; kc < 13; ++kc) {
        const int k = kc * 32;
        union { short8 v; unsigned long long u[2]; } au0, au1;
        const unsigned long long* p0 = (const unsigned long long*)(x_s + a0 + k);
        const unsigned long long* p1 = (const unsigned long long*)(x_s + a1 + k);
        au0.u[0] = p0[0]; au0.u[1] = p0[1];
        au1.u[0] = p1[0]; au1.u[1] = p1[1];
        #pragma unroll
        for (int ni = 0; ni < 4; ++ni) {
            const short8 bf = *(const short8*)(&w_s[boff[ni] + k]);
            acc[0][ni] = __builtin_amdgcn_mfma_f32_16x16x32_bf16(au0.v, bf, acc[0][ni], 0, 0, 0);
            acc[1][ni] = __builtin_amdgcn_mfma_f32_16x16x32_bf16(au1.v, bf, acc[1][ni], 0, 0, 0);
        }
    }
    float* ob = out + (size_t)b * C_OUT * NF;
    const int f_base = mt * BM + wv * 32 + q * 4;
    const int c_base = nt * BN + lm;
    #pragma unroll
    for (int mi = 0; mi < 2; ++mi) {
        #pragma unroll
        for (int ni = 0; ni < 4; ++ni) {
            const int cg = c_base + ni * 16;
            if (cg < C_OUT) {
                float* op = ob + (size_t)cg * NF;
                #pragma unroll
                for (int r = 0; r < 4; ++r) {
                    const int fg = f_base + mi * 16 + r;
                    if (fg < NF) op[fg] = acc[mi][ni][r];
                }
            }
        }
    }
}

extern "C" void kernel_launch(void* const* d_in, const int* in_sizes, int n_in,
                              void* d_out, int out_size, void* d_ws, size_t ws_size,
                              hipStream_t stream) {
    const float* x = (const float*)d_in[0];   // [32, 480000] fp32
    const float* w = (const float*)d_in[1];   // [514, 1, 400] fp32
    float* out = (float*)d_out;               // [32, 514, 4803] fp32

    if (ws_size >= WS_NEEDED) {
        unsigned short* xp = (unsigned short*)d_ws;
        unsigned short* wp = (unsigned short*)((char*)d_ws + WP_BYTE_OFF);
        cvt_x_kernel<<<XP_TOTAL / 4 / 256, 256, 0, stream>>>(x, xp);
        cvt_w_kernel<<<(WP_ELEMS + 255) / 256, 256, 0, stream>>>(w, wp);
        stft_gemm<<<dim3(NBLK), 512, 0, stream>>>(xp, wp, out);
    } else {
        dim3 grid(NT_CNT, MT_CNT, 32);
        conv_stft_fallback<<<grid, 256, 0, stream>>>(x, w, out);
    }
}